// Round 2
// baseline (53.144 us; speedup 1.0000x reference)
//
#include <hip/hip_runtime.h>

#define TWO_PI 6.2831853071795864769f

// One kernel, one block per (h,b) chain: 72 blocks x 1024 threads.
// thread = (q in 0..3, e in 0..255); thread register-caches m[d][e] for
// d in [q*64, q*64+64), where m = P1 + 0.975*P3 (dense part, NO zeroing).
// Scatter handled as sparse corrections (val_s - P1[pos]) at last-write-wins
// winner positions, resolved per-block in LDS.
__global__ __launch_bounds__(1024) void fused_chain(
    const float* __restrict__ P1, const float* __restrict__ P2,
    const float* __restrict__ P3, const float* __restrict__ T4,
    const int* __restrict__ p5, const int* __restrict__ p6,
    const int* __restrict__ p7, const int* __restrict__ p8,
    const float* __restrict__ f1, const float* __restrict__ ph1,
    const float* __restrict__ T11, const float* __restrict__ f2,
    const float* __restrict__ ph2, const float* __restrict__ T14,
    const float* __restrict__ f3, const float* __restrict__ ph3,
    float* __restrict__ out, int K)
{
    __shared__ float v[256];          // current stage input vector (per chain)
    __shared__ float pv[4][256];      // partial sums per quarter
    __shared__ float modl[3][256];    // modulation (pre-inverted for s=0,2)
    __shared__ int   ckey[2048];      // compacted (d<<8|e) for this block's b
    __shared__ int   ckidx[2048];     // original k of compacted entry
    __shared__ int   wde[2048];       // winner (d<<8|e)
    __shared__ float wv0[2048], wv1[2048], wv2[2048];  // per-stage corrections
    __shared__ int   wcnt[16];
    __shared__ int   nw;

    const int blk = blockIdx.x;
    const int h = blk / 6, b = blk - h * 6;
    const int tid = (int)threadIdx.x;
    const int e = tid & 255;
    const int q = tid >> 8;

    // ---- issue dense m loads early (512 KB/block, coalesced 256B/instr) ----
    const float* p1b = P1 + (((b << 8) + (q << 6)) << 8) + e;
    const float* p3b = P3 + (((b << 8) + (q << 6)) << 8) + e;
    float m[64];
    #pragma unroll
    for (int i = 0; i < 64; ++i)
        m[i] = fmaf(p3b[i << 8], 0.975f, p1b[i << 8]);

    // ---- small init work (overlaps with loads) ----
    if (q == 0) v[e] = P2[(h * 6 + b) * 256 + e];
    if (tid < 768) {
        int s = tid >> 8, ee = tid & 255;
        float fr = (s == 0) ? f1[0]  : (s == 1) ? f2[0]  : f3[0];
        float ph = (s == 0) ? ph1[0] : (s == 1) ? ph2[0] : ph3[0];
        float sn = sinf((float)ee * TWO_PI * fr + ph);
        float mm = sn * sn * 0.1f + 0.95f;
        modl[s][ee] = (s == 1) ? mm : 1.0f / mm;   // stage0: /m, stage1: *m, stage2: /m
    }
    if (tid == 0) nw = 0;

    // ---- stable stream-compaction of this block's b-matching scatter triples ----
    int n0 = 0;
    for (int k0 = 0; k0 < K; k0 += 1024) {
        int k = k0 + tid;
        bool valid = (k < K) && (p5[k] == b);
        int key = 0;
        if (valid) key = (p7[k] << 8) | p8[k];
        unsigned long long mask = __ballot(valid);
        int lane = tid & 63, wv = tid >> 6;
        if (lane == 0) wcnt[wv] = __popcll(mask);
        __syncthreads();
        int base = n0;
        for (int w = 0; w < wv; ++w) base += wcnt[w];
        int tot = 0;
        for (int w = 0; w < 16; ++w) tot += wcnt[w];
        if (valid) {
            int idx = base + __popcll(mask & ((1ull << lane) - 1ull));
            ckey[idx]  = key;
            ckidx[idx] = k;
        }
        n0 += tot;
        __syncthreads();
    }

    // ---- last-write-wins: entry i wins iff no j>i with same (d,e) ----
    for (int i = tid; i < n0; i += 1024) {
        int key = ckey[i];
        bool win = true;
        for (int j = i + 1; j < n0; ++j)
            if (ckey[j] == key) { win = false; break; }
        if (win) {
            int k = ckidx[i];
            int c = p6[k];
            int d = key >> 8, ee = key & 255;
            int pos = (((b << 8) | d) << 8) | ee;
            float p1v = P1[pos];
            int w = atomicAdd(&nw, 1);
            wde[w] = key;
            wv0[w] = T4 [b * 256 + c] - p1v;
            wv1[w] = T11[b * 256 + c] - p1v;
            wv2[w] = T14[b * 256 + c] - p1v;
        }
    }
    __syncthreads();

    // ---- three chained stages, all in registers/LDS ----
    const int dq = q << 6;
    const int nwl = nw;
    for (int s = 0; s < 3; ++s) {
        float a0 = 0.f, a1 = 0.f, a2 = 0.f, a3 = 0.f;
        #pragma unroll
        for (int i = 0; i < 64; i += 4) {
            a0 = fmaf(m[i    ], v[dq + i    ], a0);
            a1 = fmaf(m[i + 1], v[dq + i + 1], a1);
            a2 = fmaf(m[i + 2], v[dq + i + 2], a2);
            a3 = fmaf(m[i + 3], v[dq + i + 3], a3);
        }
        pv[q][e] = (a0 + a1) + (a2 + a3);
        __syncthreads();
        if (tid < 256)
            pv[0][tid] = (pv[0][tid] + pv[1][tid]) + (pv[2][tid] + pv[3][tid]);
        __syncthreads();
        const float* wvs = (s == 0) ? wv0 : (s == 1) ? wv1 : wv2;
        for (int i = tid; i < nwl; i += 1024) {
            int de = wde[i];
            atomicAdd(&pv[0][de & 255], v[de >> 8] * wvs[i]);
        }
        __syncthreads();
        if (tid < 256)
            v[tid] = pv[0][tid] * modl[s][tid];
        __syncthreads();
    }
    if (tid < 256) out[(h * 6 + b) * 256 + tid] = v[tid];
}

extern "C" void kernel_launch(void* const* d_in, const int* in_sizes, int n_in,
                              void* d_out, int out_size, void* d_ws, size_t ws_size,
                              hipStream_t stream)
{
    (void)n_in; (void)out_size; (void)d_ws; (void)ws_size;
    const float* P1  = (const float*)d_in[0];
    const float* P2  = (const float*)d_in[1];
    const float* P3  = (const float*)d_in[2];
    const float* T4  = (const float*)d_in[3];
    const int*   p5  = (const int*)d_in[4];
    const int*   p6  = (const int*)d_in[5];
    const int*   p7  = (const int*)d_in[6];
    const int*   p8  = (const int*)d_in[7];
    const float* f1  = (const float*)d_in[8];
    const float* ph1 = (const float*)d_in[9];
    const float* T11 = (const float*)d_in[10];
    const float* f2  = (const float*)d_in[11];
    const float* ph2 = (const float*)d_in[12];
    const float* T14 = (const float*)d_in[13];
    const float* f3  = (const float*)d_in[14];
    const float* ph3 = (const float*)d_in[15];
    float* out = (float*)d_out;
    int K = in_sizes[4];

    hipLaunchKernelGGL(fused_chain, dim3(72), dim3(1024), 0, stream,
                       P1, P2, P3, T4, p5, p6, p7, p8,
                       f1, ph1, T11, f2, ph2, T14, f3, ph3, out, K);
}

// Round 3
// 25.135 us; speedup vs baseline: 2.1144x; 2.1144x over previous
//
#include <hip/hip_runtime.h>

#define TWO_PI 6.2831853071795864769f

// One kernel, one block per (h,b) chain: 72 blocks x 1024 threads.
// thread = (q in 0..3, e in 0..255); register-caches m[d][e] for
// d in [q*64, q*64+64), m = P1 + 0.975*P3 (dense, NO zeroing).
// Scatter = sparse corrections (val_s - P1[pos]) at last-write-wins winners,
// resolved per-block via LDS hash map.
// __launch_bounds__(1024,4): 4 waves/EU min -> 128 VGPR cap -> m[64] fits,
// no scratch spill (round-2 failure mode: VGPR=64, m spilled, 53us).
__global__ __launch_bounds__(1024, 4) void fused_chain(
    const float* __restrict__ P1, const float* __restrict__ P2,
    const float* __restrict__ P3, const float* __restrict__ T4,
    const int* __restrict__ p5, const int* __restrict__ p6,
    const int* __restrict__ p7, const int* __restrict__ p8,
    const float* __restrict__ f1, const float* __restrict__ ph1,
    const float* __restrict__ T11, const float* __restrict__ f2,
    const float* __restrict__ ph2, const float* __restrict__ T14,
    const float* __restrict__ f3, const float* __restrict__ ph3,
    float* __restrict__ out, int K)
{
    __shared__ float v[256];
    __shared__ float pv[4][256];
    __shared__ float modl[3][256];
    __shared__ unsigned pk[2048];           // (p5<<24)|(p6<<16)|(p7<<8)|p8
    __shared__ unsigned short clist[2048];  // compacted k for this block's b
    __shared__ unsigned hmap[2048];         // (key<<16)|i  winner map
    __shared__ unsigned short wde[2048];    // winner key (d<<8)|e
    __shared__ float wv0[2048], wv1[2048], wv2[2048];
    __shared__ int n0s, nw;

    const int blk = blockIdx.x;
    const int h = blk / 6;
    const int b = blk - h * 6;
    const int tid = (int)threadIdx.x;
    const int e = tid & 255;
    const int q = tid >> 8;

    // ---- phase 1: issue all global loads ----
    for (int k = tid; k < K; k += 1024)
        pk[k] = ((unsigned)p5[k] << 24) | ((unsigned)p6[k] << 16) |
                ((unsigned)p7[k] << 8) | (unsigned)p8[k];

    const float* p1b = P1 + (((b << 8) + (q << 6)) << 8) + e;
    const float* p3b = P3 + (((b << 8) + (q << 6)) << 8) + e;
    float m[64];
    #pragma unroll
    for (int i = 0; i < 64; ++i)
        m[i] = fmaf(p3b[i << 8], 0.975f, p1b[i << 8]);

    if (tid < 256) v[tid] = P2[(h * 6 + b) * 256 + tid];
    if (tid < 768) {
        int s = tid >> 8, ee = tid & 255;
        float fr = (s == 0) ? f1[0]  : (s == 1) ? f2[0]  : f3[0];
        float ph = (s == 0) ? ph1[0] : (s == 1) ? ph2[0] : ph3[0];
        float sn = sinf((float)ee * TWO_PI * fr + ph);
        float mm = sn * sn * 0.1f + 0.95f;
        modl[s][ee] = (s == 1) ? mm : 1.0f / mm;  // s0: /m, s1: *m, s2: /m
    }
    for (int i = tid; i < 2048; i += 1024) hmap[i] = 0xFFFFFFFFu;
    if (tid == 0) nw = 0;
    __syncthreads();

    // ---- phase 2: single-wave stable compaction (race-free) ----
    if (tid < 64) {
        int n0 = 0;
        for (int k0 = 0; k0 < K; k0 += 64) {
            int k = k0 + tid;
            bool valid = (k < K) && ((pk[k] >> 24) == (unsigned)b);
            unsigned long long mask = __ballot(valid);
            if (valid)
                clist[n0 + __popcll(mask & ((1ull << tid) - 1ull))] =
                    (unsigned short)k;
            n0 += __popcll(mask);
        }
        if (tid == 0) n0s = n0;
    }
    __syncthreads();
    const int n0 = n0s;

    // ---- phase 3: last-write-wins via LDS hash (max i per key) ----
    for (int i = tid; i < n0; i += 1024) {
        unsigned key = pk[clist[i]] & 0xFFFFu;
        unsigned mine = (key << 16) | (unsigned)i;
        unsigned hh = (key * 2654435761u) >> 21;   // 11 bits -> [0,2048)
        for (;;) {
            unsigned prev = atomicCAS(&hmap[hh], 0xFFFFFFFFu, mine);
            if (prev == 0xFFFFFFFFu) break;
            if ((prev >> 16) == key) { atomicMax(&hmap[hh], mine); break; }
            hh = (hh + 1) & 2047u;
        }
    }
    __syncthreads();
    for (int i = tid; i < n0; i += 1024) {
        unsigned kk = clist[i];
        unsigned pkk = pk[kk];
        unsigned key = pkk & 0xFFFFu;
        unsigned hh = (key * 2654435761u) >> 21;
        unsigned cur;
        for (;;) {
            cur = hmap[hh];
            if ((cur >> 16) == key) break;
            hh = (hh + 1) & 2047u;
        }
        if ((cur & 0xFFFFu) == (unsigned)i) {      // winner
            int c = (int)((pkk >> 16) & 0xFFu);
            float p1v = P1[(b << 16) | key];        // b*65536 + d*256 + e
            int w = atomicAdd(&nw, 1);
            wde[w] = (unsigned short)key;
            wv0[w] = T4 [b * 256 + c] - p1v;
            wv1[w] = T11[b * 256 + c] - p1v;
            wv2[w] = T14[b * 256 + c] - p1v;
        }
    }
    __syncthreads();
    const int nwl = nw;

    // ---- phase 4: three chained stages, all registers/LDS ----
    const int dq = q << 6;
    for (int s = 0; s < 3; ++s) {
        float a0 = 0.f, a1 = 0.f, a2 = 0.f, a3 = 0.f;
        #pragma unroll
        for (int i = 0; i < 64; i += 4) {
            a0 = fmaf(m[i    ], v[dq + i    ], a0);
            a1 = fmaf(m[i + 1], v[dq + i + 1], a1);
            a2 = fmaf(m[i + 2], v[dq + i + 2], a2);
            a3 = fmaf(m[i + 3], v[dq + i + 3], a3);
        }
        pv[q][e] = (a0 + a1) + (a2 + a3);
        __syncthreads();
        if (tid < 256)
            pv[0][tid] = (pv[0][tid] + pv[1][tid]) + (pv[2][tid] + pv[3][tid]);
        __syncthreads();
        const float* wvs = (s == 0) ? wv0 : (s == 1) ? wv1 : wv2;
        for (int i = tid; i < nwl; i += 1024) {
            unsigned de = wde[i];
            atomicAdd(&pv[0][de & 255u], v[de >> 8] * wvs[i]);
        }
        __syncthreads();
        if (tid < 256)
            v[tid] = pv[0][tid] * modl[s][tid];
        __syncthreads();
    }
    if (tid < 256) out[(h * 6 + b) * 256 + tid] = v[tid];
}

extern "C" void kernel_launch(void* const* d_in, const int* in_sizes, int n_in,
                              void* d_out, int out_size, void* d_ws, size_t ws_size,
                              hipStream_t stream)
{
    (void)n_in; (void)out_size; (void)d_ws; (void)ws_size;
    const float* P1  = (const float*)d_in[0];
    const float* P2  = (const float*)d_in[1];
    const float* P3  = (const float*)d_in[2];
    const float* T4  = (const float*)d_in[3];
    const int*   p5  = (const int*)d_in[4];
    const int*   p6  = (const int*)d_in[5];
    const int*   p7  = (const int*)d_in[6];
    const int*   p8  = (const int*)d_in[7];
    const float* f1  = (const float*)d_in[8];
    const float* ph1 = (const float*)d_in[9];
    const float* T11 = (const float*)d_in[10];
    const float* f2  = (const float*)d_in[11];
    const float* ph2 = (const float*)d_in[12];
    const float* T14 = (const float*)d_in[13];
    const float* f3  = (const float*)d_in[14];
    const float* ph3 = (const float*)d_in[15];
    float* out = (float*)d_out;
    int K = in_sizes[4];

    hipLaunchKernelGGL(fused_chain, dim3(72), dim3(1024), 0, stream,
                       P1, P2, P3, T4, p5, p6, p7, p8,
                       f1, ph1, T11, f2, ph2, T14, f3, ph3, out, K);
}

// Round 4
// 22.674 us; speedup vs baseline: 2.3438x; 1.1085x over previous
//
#include <hip/hip_runtime.h>

#define TWO_PI 6.2831853071795864769f

// One kernel, one block per (h,b) chain: 72 blocks x 1024 threads.
// thread = (dg 0..15, eg 0..63): register-caches m4[i] = m[dg*16+i][eg*4..+3]
// (float4), m = P1 + 0.975*P3 (dense, NO zeroing). Scatter handled as sparse
// corrections (val_s - P1[pos]) at last-write-wins winners, resolved per-block
// by a direct LDS hash over all K (key=(d,e), payload=k, atomicMax).
// __launch_bounds__(1024,4): 128-VGPR cap, m4[16] fits without scratch.
__global__ __launch_bounds__(1024, 4) void fused_chain(
    const float* __restrict__ P1, const float* __restrict__ P2,
    const float* __restrict__ P3, const float* __restrict__ T4,
    const int* __restrict__ p5, const int* __restrict__ p6,
    const int* __restrict__ p7, const int* __restrict__ p8,
    const float* __restrict__ f1, const float* __restrict__ ph1,
    const float* __restrict__ T11, const float* __restrict__ f2,
    const float* __restrict__ ph2, const float* __restrict__ T14,
    const float* __restrict__ f3, const float* __restrict__ ph3,
    float* __restrict__ out, int K)
{
    __shared__ float v[256];
    __shared__ float pv[16][256];          // 16 KB partials
    __shared__ float modl[3][256];
    __shared__ unsigned hmap[4096];        // (key<<12)|k ; empty=0xFFFFFFFF
    __shared__ unsigned short wde[2048];   // winner (d<<8)|e
    __shared__ float wv0[2048], wv1[2048], wv2[2048];
    __shared__ int nw;

    const int blk = blockIdx.x;
    const int h = blk / 6;
    const int b = blk - h * 6;
    const int tid = (int)threadIdx.x;
    const int dg = tid >> 6;               // 0..15
    const int eg = tid & 63;               // 0..63

    // ---- phase 1: issue dense m loads FIRST (latency hides under hash) ----
    const float4* P1v = (const float4*)P1;
    const float4* P3v = (const float4*)P3;
    const int rbase = (b << 8) + (dg << 4);
    float4 m4[16];
    #pragma unroll
    for (int i = 0; i < 16; ++i) {
        float4 a = P1v[(rbase + i) * 64 + eg];
        float4 c = P3v[(rbase + i) * 64 + eg];
        m4[i].x = fmaf(c.x, 0.975f, a.x);
        m4[i].y = fmaf(c.y, 0.975f, a.y);
        m4[i].z = fmaf(c.z, 0.975f, a.z);
        m4[i].w = fmaf(c.w, 0.975f, a.w);
    }

    // ---- small init (overlaps with loads) ----
    if (tid < 256) v[tid] = P2[(h * 6 + b) * 256 + tid];
    if (tid < 768) {
        int s = tid >> 8, ee = tid & 255;
        float fr = (s == 0) ? f1[0]  : (s == 1) ? f2[0]  : f3[0];
        float ph = (s == 0) ? ph1[0] : (s == 1) ? ph2[0] : ph3[0];
        float sn = sinf((float)ee * TWO_PI * fr + ph);
        float mm = sn * sn * 0.1f + 0.95f;
        modl[s][ee] = (s == 1) ? mm : 1.0f / mm;   // s0: /m, s1: *m, s2: /m
    }
    for (int i = tid; i < 4096; i += 1024) hmap[i] = 0xFFFFFFFFu;
    if (tid == 0) nw = 0;
    __syncthreads();

    // ---- phase 2: direct hash insert, last-write-wins = max k per (d,e) ----
    for (int k = tid; k < K; k += 1024) {
        if (p5[k] != b) continue;
        unsigned key = ((unsigned)p7[k] << 8) | (unsigned)p8[k];   // 16 bits
        unsigned mine = (key << 12) | (unsigned)k;                 // k < 4096
        unsigned hh = (key * 2654435761u) >> 20;                   // [0,4096)
        for (;;) {
            unsigned prev = atomicCAS(&hmap[hh], 0xFFFFFFFFu, mine);
            if (prev == 0xFFFFFFFFu) break;
            if ((prev >> 12) == key) { atomicMax(&hmap[hh], mine); break; }
            hh = (hh + 1) & 4095u;
        }
    }
    __syncthreads();

    // ---- phase 3: winner readback -> sparse corrections ----
    for (int k = tid; k < K; k += 1024) {
        if (p5[k] != b) continue;
        unsigned key = ((unsigned)p7[k] << 8) | (unsigned)p8[k];
        unsigned hh = (key * 2654435761u) >> 20;
        unsigned cur;
        for (;;) {
            cur = hmap[hh];
            if ((cur >> 12) == key) break;
            hh = (hh + 1) & 4095u;
        }
        if ((cur & 0xFFFu) == (unsigned)k) {        // winner (last write)
            int c = p6[k];
            float p1v = P1[(b << 16) | key];        // b*65536 + d*256 + e
            int w = atomicAdd(&nw, 1);
            wde[w] = (unsigned short)key;
            wv0[w] = T4 [b * 256 + c] - p1v;
            wv1[w] = T11[b * 256 + c] - p1v;
            wv2[w] = T14[b * 256 + c] - p1v;
        }
    }
    __syncthreads();
    const int nwl = nw;

    // ---- phase 4: three chained stages ----
    const int e256 = tid & 255;
    for (int s = 0; s < 3; ++s) {
        float4 acc = make_float4(0.f, 0.f, 0.f, 0.f);
        #pragma unroll
        for (int j = 0; j < 4; ++j) {
            float4 vv = *(const float4*)&v[(dg << 4) + (j << 2)];
            float4 m0 = m4[(j << 2) + 0];
            float4 m1 = m4[(j << 2) + 1];
            float4 m2 = m4[(j << 2) + 2];
            float4 m3 = m4[(j << 2) + 3];
            acc.x = fmaf(vv.x, m0.x, acc.x); acc.y = fmaf(vv.x, m0.y, acc.y);
            acc.z = fmaf(vv.x, m0.z, acc.z); acc.w = fmaf(vv.x, m0.w, acc.w);
            acc.x = fmaf(vv.y, m1.x, acc.x); acc.y = fmaf(vv.y, m1.y, acc.y);
            acc.z = fmaf(vv.y, m1.z, acc.z); acc.w = fmaf(vv.y, m1.w, acc.w);
            acc.x = fmaf(vv.z, m2.x, acc.x); acc.y = fmaf(vv.z, m2.y, acc.y);
            acc.z = fmaf(vv.z, m2.z, acc.z); acc.w = fmaf(vv.z, m2.w, acc.w);
            acc.x = fmaf(vv.w, m3.x, acc.x); acc.y = fmaf(vv.w, m3.y, acc.y);
            acc.z = fmaf(vv.w, m3.z, acc.z); acc.w = fmaf(vv.w, m3.w, acc.w);
        }
        *(float4*)&pv[dg][eg << 2] = acc;
        __syncthreads();
        {   // reduce 16 -> 4 rows
            int r = tid >> 8;                       // 0..3
            float x = pv[r][e256] + pv[r + 4][e256] +
                      pv[r + 8][e256] + pv[r + 12][e256];
            __syncthreads();
            pv[r][e256] = x;
        }
        __syncthreads();
        if (tid < 256)                              // reduce 4 -> 1
            pv[0][tid] = (pv[0][tid] + pv[1][tid]) + (pv[2][tid] + pv[3][tid]);
        __syncthreads();
        const float* wvs = (s == 0) ? wv0 : (s == 1) ? wv1 : wv2;
        for (int i = tid; i < nwl; i += 1024) {
            unsigned de = wde[i];
            atomicAdd(&pv[0][de & 255u], v[de >> 8] * wvs[i]);
        }
        __syncthreads();
        if (tid < 256)
            v[tid] = pv[0][tid] * modl[s][tid];
        __syncthreads();
    }
    if (tid < 256) out[(h * 6 + b) * 256 + tid] = v[tid];
}

extern "C" void kernel_launch(void* const* d_in, const int* in_sizes, int n_in,
                              void* d_out, int out_size, void* d_ws, size_t ws_size,
                              hipStream_t stream)
{
    (void)n_in; (void)out_size; (void)d_ws; (void)ws_size;
    const float* P1  = (const float*)d_in[0];
    const float* P2  = (const float*)d_in[1];
    const float* P3  = (const float*)d_in[2];
    const float* T4  = (const float*)d_in[3];
    const int*   p5  = (const int*)d_in[4];
    const int*   p6  = (const int*)d_in[5];
    const int*   p7  = (const int*)d_in[6];
    const int*   p8  = (const int*)d_in[7];
    const float* f1  = (const float*)d_in[8];
    const float* ph1 = (const float*)d_in[9];
    const float* T11 = (const float*)d_in[10];
    const float* f2  = (const float*)d_in[11];
    const float* ph2 = (const float*)d_in[12];
    const float* T14 = (const float*)d_in[13];
    const float* f3  = (const float*)d_in[14];
    const float* ph3 = (const float*)d_in[15];
    float* out = (float*)d_out;
    int K = in_sizes[4];

    hipLaunchKernelGGL(fused_chain, dim3(72), dim3(1024), 0, stream,
                       P1, P2, P3, T4, p5, p6, p7, p8,
                       f1, ph1, T11, f2, ph2, T14, f3, ph3, out, K);
}